// Round 8
// baseline (272.002 us; speedup 1.0000x reference)
//
#include <hip/hip_runtime.h>

#define T_LEN 1024

typedef _Float16 f16x8 __attribute__((ext_vector_type(8)));
typedef float    f32x4 __attribute__((ext_vector_type(4)));

__device__ __forceinline__ _Float16 exp2_h(_Float16 v) {
    _Float16 o;
    asm("v_exp_f16 %0, %1" : "=v"(o) : "v"(v));
    return o;
}
__device__ __forceinline__ _Float16 rcp_h(_Float16 v) {
    _Float16 o;
    asm("v_rcp_f16 %0, %1" : "=v"(o) : "v"(v));
    return o;
}

// One wave (64 threads) per block; block owns 16 batch rows for all T steps.
// Recurrence in "r-space": h = 1 - 2r where r = 1/(exp2(t)+1), t = K*v, K=2log2e.
// Substituting h into v = x*Wih + b + W_hh h gives
//   t[c] = K*(x*Wih[c] + b[c] + rowsum(W_hh[c,:])) + sum_k (-2K*W_hh[c,k]) * r[k]
// so the MFMA A-fragment is -2K*W_hh (f16) and r recirculates as the B-fragment.
//   A-frag: A[m=lane&15][k=quad*8+j] = -2K*Whh[sigma(m)][k]
//   B-frag: B[k=quad*8+j][n=lane&15] = r[row n][k]
//   C-frag: col n=lane&15 (batch row), row m=quad*4+reg; sigma0(m)=8*(m>>2)+(m&3),
//   sigma1=sigma0+4 ==> lane's C outputs are exactly its own B slots next step.
// tanh entirely in f16: cvt -> v_exp_f16 -> add -> v_rcp_f16. Saturation is free:
// t>=16 => e=inf => r=0 (h=1); t<<0 => e=0 => r=1 (h=-1). No clamps, no final fma.
__global__ __launch_bounds__(64) void rnn_fused(
    const float* __restrict__ x,      // [B, T]
    const float* __restrict__ W_ih,   // [32,1]
    const float* __restrict__ W_hh,   // [32,32]
    const float* __restrict__ b_ih,   // [32]
    const float* __restrict__ b_hh,   // [32]
    const float* __restrict__ fc_w,   // [1,32]
    const float* __restrict__ fc_b,   // [1]
    float* __restrict__ out)          // [B]
{
    const int lane = threadIdx.x;
    const int n = lane & 15;   // batch row within tile (B-frag col / C col)
    const int q = lane >> 4;   // quad index

    const float K = 2.88539008177792681472f;   // 2*log2(e)

    // A fragments: -2K * W_hh rows (permuted by sigma), f16.
    const int c0row = 8 * (n >> 2) + (n & 3);
    const int c1row = c0row + 4;
    f16x8 a0, a1;
#pragma unroll
    for (int j = 0; j < 8; ++j) {
        a0[j] = (_Float16)(-2.0f * K * W_hh[c0row * 32 + q * 8 + j]);
        a1[j] = (_Float16)(-2.0f * K * W_hh[c1row * 32 + q * 8 + j]);
    }

    // This lane produces h-columns c = 8q + i (i = 0..7).
    // bias' = K*(b_ih + b_hh + rowsum(W_hh[c,:]))  (r-space fold)
    float wih[8], bias[8];
#pragma unroll
    for (int i = 0; i < 8; ++i) {
        int c = 8 * q + i;
        float rs = 0.0f;
        for (int k = 0; k < 32; ++k) rs += W_hh[c * 32 + k];
        wih[i]  = K * W_ih[c];
        bias[i] = K * (b_ih[c] + b_hh[c] + rs);
    }

    const float* xrow = x + (size_t)(blockIdx.x * 16 + n) * T_LEN;
    float4 xa = *(const float4*)xrow;   // t = 0..3 (4 lanes/row redundant -> broadcast)

    // B fragment holds r; h=0 <=> r=0.5
    f16x8 hb;
#pragma unroll
    for (int i = 0; i < 8; ++i) hb[i] = (_Float16)0.5f;

    const _Float16 oneh = (_Float16)1.0f;

    for (int t4 = 0; t4 < T_LEN / 4; ++t4) {
        const int nt4 = (t4 < T_LEN / 4 - 1) ? t4 + 1 : t4;   // prefetch next x chunk
        float4 xn = *(const float4*)(xrow + (size_t)nt4 * 4);
#pragma unroll
        for (int p = 0; p < 4; ++p) {
            const float xt = (p == 0) ? xa.x : (p == 1) ? xa.y : (p == 2) ? xa.z : xa.w;
            f32x4 acc0, acc1;
#pragma unroll
            for (int i = 0; i < 4; ++i) {
                acc0[i] = fmaf(xt, wih[i],     bias[i]);   // C-init = K*(x*Wih + b + rowsum)
                acc1[i] = fmaf(xt, wih[4 + i], bias[4 + i]);
            }
            acc0 = __builtin_amdgcn_mfma_f32_16x16x32_f16(a0, hb, acc0, 0, 0, 0);
            acc1 = __builtin_amdgcn_mfma_f32_16x16x32_f16(a1, hb, acc1, 0, 0, 0);

            // f16 tanh pipeline (r-space): cvt -> exp_f16 -> add -> rcp_f16
            _Float16 t0 = (_Float16)acc0[0], t1 = (_Float16)acc0[1];
            _Float16 t2 = (_Float16)acc0[2], t3 = (_Float16)acc0[3];
            _Float16 t4h = (_Float16)acc1[0], t5 = (_Float16)acc1[1];
            _Float16 t6 = (_Float16)acc1[2], t7 = (_Float16)acc1[3];
            _Float16 e0 = exp2_h(t0), e1 = exp2_h(t1), e2 = exp2_h(t2), e3 = exp2_h(t3);
            _Float16 e4 = exp2_h(t4h), e5 = exp2_h(t5), e6 = exp2_h(t6), e7 = exp2_h(t7);
            _Float16 d0 = e0 + oneh, d1 = e1 + oneh, d2 = e2 + oneh, d3 = e3 + oneh;
            _Float16 d4 = e4 + oneh, d5 = e5 + oneh, d6 = e6 + oneh, d7 = e7 + oneh;
            f16x8 nb;
            nb[0] = rcp_h(d0); nb[1] = rcp_h(d1); nb[2] = rcp_h(d2); nb[3] = rcp_h(d3);
            nb[4] = rcp_h(d4); nb[5] = rcp_h(d5); nb[6] = rcp_h(d6); nb[7] = rcp_h(d7);
            hb = nb;
        }
        xa = xn;
    }

    // Head: h = 1 - 2r; out[row] = sum_c h[c] * fc_w[c] + fc_b
    float part = 0.0f;
#pragma unroll
    for (int i = 0; i < 8; ++i) {
        float h = fmaf(-2.0f, (float)hb[i], 1.0f);
        part = fmaf(h, fc_w[8 * q + i], part);
    }
    part += __shfl_xor(part, 16);
    part += __shfl_xor(part, 32);
    if (q == 0) out[blockIdx.x * 16 + n] = part + fc_b[0];
}

extern "C" void kernel_launch(void* const* d_in, const int* in_sizes, int n_in,
                              void* d_out, int out_size, void* d_ws, size_t ws_size,
                              hipStream_t stream) {
    const float* x    = (const float*)d_in[0];
    const float* W_ih = (const float*)d_in[1];
    const float* W_hh = (const float*)d_in[2];
    const float* b_ih = (const float*)d_in[3];
    const float* b_hh = (const float*)d_in[4];
    const float* fc_w = (const float*)d_in[5];
    const float* fc_b = (const float*)d_in[6];
    float* out = (float*)d_out;

    const int B = in_sizes[0] / T_LEN;   // 16384
    rnn_fused<<<B / 16, 64, 0, stream>>>(x, W_ih, W_hh, b_ih, b_hh, fc_w, fc_b, out);
}